// Round 4
// baseline (175.277 us; speedup 1.0000x reference)
//
#include <hip/hip_runtime.h>
#include <cstdint>
#include <cstddef>

// Problem shape (fixed by setup_inputs): hidden [4,2048,2048] -> M=8192, K=2048, N=2048
#define MDIM 8192
#define NDIM 2048
#define KDIM 2048

constexpr int BM = 128, BN = 128, BK = 64;   // 128^2 tile, 4-deep LDS ring = 64 KB -> 2 blocks/CU
constexpr int NT = KDIM / BK;                // 32 k-tiles
constexpr int NBUF = 4;

typedef int v4i __attribute__((ext_vector_type(4)));

__device__ __forceinline__ void async_ld16(const void* g, void* l) {
    __builtin_amdgcn_global_load_lds(
        (const __attribute__((address_space(1))) int*)g,
        (__attribute__((address_space(3))) int*)l,
        16, 0, 0);
}

// ---------- fused quantize: x fp32 -> int8 (packed u32)  +  W fp32 [K][N] -> int8 [N][K] ----------
__device__ __forceinline__ uint32_t q8(float x, float inv) {
    float q = fminf(fmaxf(rintf(x * inv), -127.f), 127.f);
    return (uint32_t)((int)q) & 0xffu;
}

// x-part: 4 coalesced chunks per thread (4x fewer blocks, same per-instr coalescing)
#define XCHUNK (MDIM * KDIM / 4 / 4)              // float4s per chunk = 1048576
#define XBLOCKS (XCHUNK / 256)                    // 4096 blocks

__global__ void quant_kernel(const float4* __restrict__ x, uint32_t* __restrict__ xq,
                             const float* __restrict__ scale_p,
                             const float* __restrict__ w, uint32_t* __restrict__ wt) {
    __shared__ uint32_t t[64][17];
    const int tid = threadIdx.x;

    if (blockIdx.x < XBLOCKS) {
        // ---- x quant: thread handles 4 float4s at chunk stride (all accesses coalesced) ----
        int i = blockIdx.x * 256 + tid;
        float inv = 1.0f / fmaxf(scale_p[0], 1e-8f);
#pragma unroll
        for (int k = 0; k < 4; ++k) {
            float4 v = x[i + k * XCHUNK];
            xq[i + k * XCHUNK] =
                q8(v.x, inv) | (q8(v.y, inv) << 8) | (q8(v.z, inv) << 16) | (q8(v.w, inv) << 24);
        }
        return;
    }

    // ---- W quant + transpose: 64x64 tile per block ----
    const int bid = blockIdx.x - XBLOCKS;          // 0..1023
    const int k0 = (bid >> 5) * 64;                // KDIM/64 = 32
    const int n0 = (bid & 31) * 64;                // NDIM/64 = 32
    const int rr  = tid >> 4;                      // 0..15
    const int c4  = (tid & 15) * 4;                // 0..60
#pragma unroll
    for (int p = 0; p < 4; ++p) {
        int r = rr + p * 16;
        float4 v = *(const float4*)&w[(size_t)(k0 + r) * NDIM + n0 + c4];
        uint32_t pk = (uint32_t)((int)rintf(v.x) & 0xff)
                    | ((uint32_t)((int)rintf(v.y) & 0xff) << 8)
                    | ((uint32_t)((int)rintf(v.z) & 0xff) << 16)
                    | ((uint32_t)((int)rintf(v.w) & 0xff) << 24);
        t[r][c4 >> 2] = pk;
    }
    __syncthreads();
#pragma unroll
    for (int p = 0; p < 4; ++p) {
        int c = rr + p * 16;
        uint32_t o = 0;
#pragma unroll
        for (int j = 0; j < 4; ++j) {
            uint32_t b = (t[c4 + j][c >> 2] >> ((c & 3) * 8)) & 0xffu;
            o |= b << (j * 8);
        }
        wt[((size_t)(n0 + c) * KDIM + k0 + c4) >> 2] = o;
    }
}

// ---------- i8 GEMM: C = A * Bt^T + bias; 128^2 tile, 4-deep ring, counted vmcnt, 2 blk/CU ----------
// LDS tile row = 64B = 4 x 16B chunks; chunk c of row r stored at slot c ^ ((r>>1)&3)
// (verified conflict-free: SQ_LDS_BANK_CONFLICT == 0 across all predecessors).
__global__ __launch_bounds__(256, 2)
void gemm_i8_kernel(const int8_t* __restrict__ A,   // [M][K] int8
                    const int8_t* __restrict__ Bt,  // [N][K] int8
                    const float* __restrict__ bias, // [N]
                    float* __restrict__ C) {        // [M][N] fp32
    __shared__ alignas(16) int8_t lA[NBUF][BM * BK];   // 4 x 8 KB
    __shared__ alignas(16) int8_t lB[NBUF][BN * BK];   // 4 x 8 KB

    const int tid  = threadIdx.x;
    const int lane = tid & 63;
    const int wave = tid >> 6;           // 0..3
    const int wm   = wave & 1;           // M-half: 64 rows
    const int wn   = wave >> 1;          // N-half: 64 cols

    // XCD-aware swizzle: 1024 blocks (%8==0, bijective), 128 contiguous tiles per XCD
    const int bidlin = blockIdx.y * gridDim.x + blockIdx.x;   // 0..1023
    const int swz    = (bidlin & 7) * 128 + (bidlin >> 3);
    const int m0     = (swz >> 4) * BM;                        // 64 M-tiles
    const int n0     = (swz & 15) * BN;                        // 16 N-tiles

    // staging: wave covers 32 rows (srow, srow+16), 4 async loads / thread / tile
    const int srow = lane >> 2;                       // 0..15
    const int schk = (lane & 3) ^ ((srow >> 1) & 3);  // swizzled source chunk
    const int8_t* gA = A  + (size_t)(m0 + wave * 32 + srow) * KDIM + schk * 16;
    const int8_t* gB = Bt + (size_t)(n0 + wave * 32 + srow) * KDIM + schk * 16;
    const int lwo = wave * 2048;

    // fragments: lane reads row (.. + lr), logical chunk quad at slot quad^((lr>>1)&3)
    const int quad = lane >> 4;
    const int lr   = lane & 15;
    const int fchk = (quad ^ ((lr >> 1) & 3)) * 16;
    const int aoff = (wm * 64 + lr) * BK + fchk;
    const int boff = (wn * 64 + lr) * BK + fchk;

    v4i acc[4][4];
#pragma unroll
    for (int i = 0; i < 4; ++i)
#pragma unroll
        for (int j = 0; j < 4; ++j)
            acc[i][j] = (v4i){0, 0, 0, 0};

#define STAGE_ALL(buf, kof)                                                    \
    do {                                                                       \
        async_ld16(gA + (kof), &lA[buf][lwo]);                                 \
        async_ld16(gA + (kof) + (size_t)16 * KDIM, &lA[buf][lwo + 1024]);      \
        async_ld16(gB + (kof), &lB[buf][lwo]);                                 \
        async_ld16(gB + (kof) + (size_t)16 * KDIM, &lB[buf][lwo + 1024]);      \
    } while (0)

    // phase p (p=0,1) of tile in buf tb: read af[2p],af[2p+1] (+bf[0..3] at p==0),
    // issue 2 stage loads, barrier, lgkmcnt(0), 8 MFMA, (tail wait), barrier
#define PHASE(tb, p, STAGE_STMT, TAIL_STMT)                                    \
    do {                                                                       \
        if ((p) == 0) {                                                        \
            _Pragma("unroll")                                                  \
            for (int j = 0; j < 4; ++j)                                        \
                bf[j] = *(const v4i*)&lB[tb][boff + j * 1024];                 \
        }                                                                      \
        v4i af0 = *(const v4i*)&lA[tb][aoff + (2 * (p)) * 1024];               \
        v4i af1 = *(const v4i*)&lA[tb][aoff + (2 * (p) + 1) * 1024];           \
        STAGE_STMT;                                                            \
        asm volatile("" ::: "memory");                                         \
        __builtin_amdgcn_s_barrier();                                          \
        asm volatile("s_waitcnt lgkmcnt(0)" ::: "memory");                     \
        __builtin_amdgcn_s_setprio(1);                                         \
        _Pragma("unroll")                                                      \
        for (int j = 0; j < 4; ++j) {                                          \
            acc[2 * (p)][j] = __builtin_amdgcn_mfma_i32_16x16x64_i8(           \
                af0, bf[j], acc[2 * (p)][j], 0, 0, 0);                         \
            acc[2 * (p) + 1][j] = __builtin_amdgcn_mfma_i32_16x16x64_i8(       \
                af1, bf[j], acc[2 * (p) + 1][j], 0, 0, 0);                     \
        }                                                                      \
        __builtin_amdgcn_s_setprio(0);                                        \
        TAIL_STMT;                                                             \
        asm volatile("" ::: "memory");                                         \
        __builtin_amdgcn_s_barrier();                                          \
    } while (0)

#define NOSTAGE ((void)0)
#define VM(n) asm volatile("s_waitcnt vmcnt(" #n ")" ::: "memory")

    // K-tile: stage tile (t+3) 2 loads per phase; vmcnt(8) once per tile (never 0 in main loop)
#define KTILE_MAIN(tb, sb, kof)                                                \
    do {                                                                       \
        v4i bf[4];                                                             \
        PHASE(tb, 0,                                                           \
              (async_ld16(gA + (kof), &lA[sb][lwo]),                           \
               async_ld16(gA + (kof) + (size_t)16 * KDIM, &lA[sb][lwo + 1024])),\
              NOSTAGE);                                                        \
        PHASE(tb, 1,                                                           \
              (async_ld16(gB + (kof), &lB[sb][lwo]),                           \
               async_ld16(gB + (kof) + (size_t)16 * KDIM, &lB[sb][lwo + 1024])),\
              VM(8));                                                          \
    } while (0)

#define KTILE_TAIL(tb, TAILW)                                                  \
    do {                                                                       \
        v4i bf[4];                                                             \
        PHASE(tb, 0, NOSTAGE, NOSTAGE);                                        \
        PHASE(tb, 1, NOSTAGE, TAILW);                                          \
    } while (0)

    // prologue: fill 3 ring stages (12 loads), wait tile 0 landed (vmcnt 8), sync
    STAGE_ALL(0, 0);
    STAGE_ALL(1, BK);
    STAGE_ALL(2, 2 * BK);
    VM(8);
    asm volatile("" ::: "memory");
    __builtin_amdgcn_s_barrier();

    // main loop: t = 0..NT-4; compute buf t&3, stage tile t+3 into buf (t+3)&3
    int kof = 3 * BK;
    for (int t = 0; t < NT - 3; ++t) {
        KTILE_MAIN(t & 3, (t + 3) & 3, kof);
        kof += BK;
    }
    // tail: tiles NT-3, NT-2, NT-1 with derived waits 4 -> 0 -> none
    KTILE_TAIL((NT - 3) & 3, VM(4));
    KTILE_TAIL((NT - 2) & 3, VM(0));
    KTILE_TAIL((NT - 1) & 3, NOSTAGE);

#undef STAGE_ALL
#undef PHASE
#undef NOSTAGE
#undef VM
#undef KTILE_MAIN
#undef KTILE_TAIL

    // epilogue: C/D layout col = lane&15, row = quad*4 + reg (verified, dtype-indep)
    const int crow = m0 + wm * 64 + quad * 4;
    const int ccol = n0 + wn * 64 + lr;
    float bj[4];
#pragma unroll
    for (int j = 0; j < 4; ++j) bj[j] = bias[ccol + j * 16];
#pragma unroll
    for (int i = 0; i < 4; ++i)
#pragma unroll
        for (int j = 0; j < 4; ++j)
#pragma unroll
            for (int r = 0; r < 4; ++r)
                C[(size_t)(crow + i * 16 + r) * NDIM + (ccol + j * 16)] = (float)acc[i][j][r] + bj[j];
}

extern "C" void kernel_launch(void* const* d_in, const int* in_sizes, int n_in,
                              void* d_out, int out_size, void* d_ws, size_t ws_size,
                              hipStream_t stream) {
    const float* x    = (const float*)d_in[0];   // [8192, 2048] fp32
    const float* w    = (const float*)d_in[1];   // [2048, 2048] fp32 (integer-valued)
    const float* xs   = (const float*)d_in[2];   // scalar
    const float* bias = (const float*)d_in[3];   // [2048]
    float* out = (float*)d_out;                  // [8192, 2048] fp32

    int8_t* xq = (int8_t*)d_ws;                          // 16 MB
    int8_t* wt = xq + (size_t)MDIM * KDIM;               //  4 MB

    quant_kernel<<<XBLOCKS + (KDIM / 64) * (NDIM / 64), 256, 0, stream>>>(
        (const float4*)x, (uint32_t*)xq, xs, w, (uint32_t*)wt);
    gemm_i8_kernel<<<dim3(NDIM / BN, MDIM / BM), 256, 0, stream>>>(xq, wt, bias, out);
}

// Round 5
// 168.895 us; speedup vs baseline: 1.0378x; 1.0378x over previous
//
#include <hip/hip_runtime.h>
#include <cstdint>
#include <cstddef>

// Problem shape (fixed by setup_inputs): hidden [4,2048,2048] -> M=8192, K=2048, N=2048
#define MDIM 8192
#define NDIM 2048
#define KDIM 2048

constexpr int BM = 128, BN = 128, BK = 64;   // dbuf: 2 x (8KB A + 8KB B) = 32 KB LDS

typedef int v4i __attribute__((ext_vector_type(4)));

__device__ __forceinline__ void async_ld16(const void* g, void* l) {
    __builtin_amdgcn_global_load_lds(
        (const __attribute__((address_space(1))) int*)g,
        (__attribute__((address_space(3))) int*)l,
        16, 0, 0);
}

// ---------- fused quantize: x fp32 -> int8 (packed u32)  +  W fp32 [K][N] -> int8 [N][K] ----------
__device__ __forceinline__ uint32_t q8(float x, float inv) {
    float q = fminf(fmaxf(rintf(x * inv), -127.f), 127.f);
    return (uint32_t)((int)q) & 0xffu;
}

// W-part first (blocks 0..1023), then x-part: 2048 blocks x 256 threads x 8 grid-strided float4
#define WBLOCKS ((KDIM / 64) * (NDIM / 64))       // 1024
#define XBLOCKS 2048
#define XSTRIDE (XBLOCKS * 256)                   // float4s per sweep = 524288
#define XITERS  (MDIM * KDIM / 4 / XSTRIDE)       // 8

__global__ void quant_kernel(const float4* __restrict__ x, uint32_t* __restrict__ xq,
                             const float* __restrict__ scale_p,
                             const float* __restrict__ w, uint32_t* __restrict__ wt) {
    __shared__ uint32_t t[64][17];
    const int tid = threadIdx.x;

    if (blockIdx.x >= WBLOCKS) {
        // ---- x quant: grid-stride, 8 float4 per thread, every access coalesced ----
        int i = (blockIdx.x - WBLOCKS) * 256 + tid;
        float inv = 1.0f / fmaxf(scale_p[0], 1e-8f);
#pragma unroll
        for (int k = 0; k < XITERS; ++k) {
            float4 v = x[i + k * XSTRIDE];
            xq[i + k * XSTRIDE] =
                q8(v.x, inv) | (q8(v.y, inv) << 8) | (q8(v.z, inv) << 16) | (q8(v.w, inv) << 24);
        }
        return;
    }

    // ---- W quant + transpose: 64x64 tile per block ----
    const int bid = blockIdx.x;                    // 0..1023
    const int k0 = (bid >> 5) * 64;                // KDIM/64 = 32
    const int n0 = (bid & 31) * 64;                // NDIM/64 = 32
    const int rr  = tid >> 4;                      // 0..15
    const int c4  = (tid & 15) * 4;                // 0..60
#pragma unroll
    for (int p = 0; p < 4; ++p) {
        int r = rr + p * 16;
        float4 v = *(const float4*)&w[(size_t)(k0 + r) * NDIM + n0 + c4];
        uint32_t pk = (uint32_t)((int)rintf(v.x) & 0xff)
                    | ((uint32_t)((int)rintf(v.y) & 0xff) << 8)
                    | ((uint32_t)((int)rintf(v.z) & 0xff) << 16)
                    | ((uint32_t)((int)rintf(v.w) & 0xff) << 24);
        t[r][c4 >> 2] = pk;
    }
    __syncthreads();
    // read side: thread owns column c = rr+p*16, rows c4..c4+3 -> one uint32 out
#pragma unroll
    for (int p = 0; p < 4; ++p) {
        int c = rr + p * 16;
        uint32_t o = 0;
#pragma unroll
        for (int j = 0; j < 4; ++j) {
            uint32_t b = (t[c4 + j][c >> 2] >> ((c & 3) * 8)) & 0xffu;
            o |= b << (j * 8);
        }
        wt[((size_t)(n0 + c) * KDIM + k0 + c4) >> 2] = o;
    }
}

// ---------- i8 GEMM: C = A * Bt^T + bias, int32 accum, BK=64 LDS double-buffer ----------
// (R0 structure, verbatim: proven 52.4 us, MfmaUtil 26, conflicts 0, 4 blocks/CU.)
// LDS tile row = 64B = 4 x 16B chunks; chunk c of row r stored at c ^ ((r>>1)&3)
// (uniform 2-way bank aliasing = free; period-4 c^(r&3) would 4-way conflict since
//  a 64B row spans only half the 32 banks).
__global__ __launch_bounds__(256, 4)
void gemm_i8_kernel(const int8_t* __restrict__ A,   // [M][K] int8
                    const int8_t* __restrict__ Bt,  // [N][K] int8
                    const float* __restrict__ bias, // [N]
                    float* __restrict__ C) {        // [M][N] fp32
    __shared__ alignas(16) int8_t lA[2][BM * BK];   // 2 x 8 KB
    __shared__ alignas(16) int8_t lB[2][BN * BK];

    const int tid  = threadIdx.x;
    const int lane = tid & 63;
    const int wave = tid >> 6;           // 0..3
    const int wm   = wave & 1;
    const int wn   = wave >> 1;
    const int m0   = blockIdx.y * BM;
    const int n0   = blockIdx.x * BN;

    // staging: wave covers rows [wave*32, +32), 2 issues x (16 rows x 64B = 1KB)
    const int srow = lane >> 2;                       // 0..15
    const int schk = (lane & 3) ^ ((srow >> 1) & 3);  // swizzled source chunk
    const int8_t* gA = A  + (size_t)(m0 + wave * 32 + srow) * KDIM + schk * 16;
    const int8_t* gB = Bt + (size_t)(n0 + wave * 32 + srow) * KDIM + schk * 16;
    const int lwo = wave * 2048;

    // fragments: lane reads row (.. + lr), global chunk quad -> LDS chunk quad^((lr>>1)&3)
    const int quad = lane >> 4;
    const int lr   = lane & 15;
    const int fchk = (quad ^ ((lr >> 1) & 3)) * 16;
    const int aoff = (wm * 64 + lr) * BK + fchk;
    const int boff = (wn * 64 + lr) * BK + fchk;

    v4i acc[4][4];
#pragma unroll
    for (int i = 0; i < 4; ++i)
#pragma unroll
        for (int j = 0; j < 4; ++j)
            acc[i][j] = (v4i){0, 0, 0, 0};

#define STAGE(buf, kof)                                                        \
    do {                                                                       \
        async_ld16(gA + (kof), &lA[buf][lwo]);                                 \
        async_ld16(gA + (kof) + (size_t)16 * KDIM, &lA[buf][lwo + 1024]);      \
        async_ld16(gB + (kof), &lB[buf][lwo]);                                 \
        async_ld16(gB + (kof) + (size_t)16 * KDIM, &lB[buf][lwo + 1024]);      \
    } while (0)

#define COMPUTE(buf)                                                           \
    do {                                                                       \
        v4i af[4], bf[4];                                                      \
        _Pragma("unroll")                                                      \
        for (int i = 0; i < 4; ++i)                                            \
            af[i] = *(const v4i*)&lA[buf][aoff + i * 16 * BK];                 \
        _Pragma("unroll")                                                      \
        for (int j = 0; j < 4; ++j)                                            \
            bf[j] = *(const v4i*)&lB[buf][boff + j * 16 * BK];                 \
        _Pragma("unroll")                                                      \
        for (int i = 0; i < 4; ++i)                                            \
            _Pragma("unroll")                                                  \
            for (int j = 0; j < 4; ++j)                                        \
                acc[i][j] = __builtin_amdgcn_mfma_i32_16x16x64_i8(             \
                    af[i], bf[j], acc[i][j], 0, 0, 0);                         \
    } while (0)

    STAGE(0, 0);
    int kof = BK;
    for (int it = 0; it < KDIM / BK - 1; ++it) {
        __syncthreads();                 // drains vmcnt: tile `it` visible; buf (it+1)&1 free
        STAGE((it + 1) & 1, kof);        // prefetch next tile (flies during compute)
        kof += BK;
        COMPUTE(it & 1);
    }
    __syncthreads();
    COMPUTE((KDIM / BK - 1) & 1);

    // epilogue: C/D layout col = lane&15, row = quad*4 + reg (verified, dtype-indep)
    const int crow = m0 + wm * 64 + quad * 4;
    const int ccol = n0 + wn * 64 + lr;
    float bj[4];
#pragma unroll
    for (int j = 0; j < 4; ++j) bj[j] = bias[ccol + j * 16];
#pragma unroll
    for (int i = 0; i < 4; ++i)
#pragma unroll
        for (int j = 0; j < 4; ++j)
#pragma unroll
            for (int r = 0; r < 4; ++r)
                C[(size_t)(crow + i * 16 + r) * NDIM + (ccol + j * 16)] = (float)acc[i][j][r] + bj[j];
}

extern "C" void kernel_launch(void* const* d_in, const int* in_sizes, int n_in,
                              void* d_out, int out_size, void* d_ws, size_t ws_size,
                              hipStream_t stream) {
    const float* x    = (const float*)d_in[0];   // [8192, 2048] fp32
    const float* w    = (const float*)d_in[1];   // [2048, 2048] fp32 (integer-valued)
    const float* xs   = (const float*)d_in[2];   // scalar
    const float* bias = (const float*)d_in[3];   // [2048]
    float* out = (float*)d_out;                  // [8192, 2048] fp32

    int8_t* xq = (int8_t*)d_ws;                          // 16 MB
    int8_t* wt = xq + (size_t)MDIM * KDIM;               //  4 MB

    quant_kernel<<<WBLOCKS + XBLOCKS, 256, 0, stream>>>(
        (const float4*)x, (uint32_t*)xq, xs, w, (uint32_t*)wt);
    gemm_i8_kernel<<<dim3(NDIM / BN, MDIM / BM), 256, 0, stream>>>(xq, wt, bias, out);
}